// Round 6
// baseline (18153.038 us; speedup 1.0000x reference)
//
#include <hip/hip_runtime.h>
#include <hip/hip_bf16.h>
#include <cstddef>
#include <cstdint>

#define NS   16384
#define HS   512
#define DS   128
#define KOBS 40
#define ES   4096
#define DTC  0.05f
#define HSTR 520   // padded LDS row stride (elems): 520%32!=0 spreads banks

typedef __bf16 bf16x8 __attribute__((ext_vector_type(8)));
typedef float  f32x4  __attribute__((ext_vector_type(4)));
typedef __hip_bfloat16 bf16_t;

__device__ __forceinline__ void async16(const void* g, void* l)
{
  __builtin_amdgcn_global_load_lds(
      (const __attribute__((address_space(1))) unsigned int*)g,
      (__attribute__((address_space(3))) unsigned int*)l, 16, 0, 0);
}

__device__ __forceinline__ float fast_tanh(float x)
{
  return 1.f - 2.f / (1.f + __expf(2.f * x));
}

// ---------------------------------------------------------------------------
// Fused Euler pass: one wave computes out[32 rows x 128 cols] of a 64x512
// strip. A from LDS-resident strip (stride HSTR); B direct-from-global
// (L2-hot weights) with 2-iteration register prefetch. No barriers.
// TANH=true:  Us = tanh(A @ B^T + bias)
// TANH=false: hs = hs + DT*(A @ B^T + bias)   (RMW on hsOut)
// ---------------------------------------------------------------------------
template <bool TANH>
__device__ __forceinline__ void euler_pass(
    const bf16_t* __restrict__ Bmat, const float* __restrict__ bias,
    const bf16_t* hsA, bf16_t* hsOut, int wv, int lane)
{
  const int q = lane >> 4, ln = lane & 15;
  const int rowbase = (wv >> 2) * 32, colbase = (wv & 3) * 128;

  float bj[8];
  const bf16_t* bp[8];
#pragma unroll
  for (int j = 0; j < 8; ++j) {
    bj[j] = bias[colbase + j * 16 + ln];
    bp[j] = Bmat + (size_t)(colbase + j * 16 + ln) * HS + q * 8;
  }

  f32x4 acc[2][8];
#pragma unroll
  for (int i = 0; i < 2; ++i)
#pragma unroll
    for (int j = 0; j < 8; ++j) acc[i][j] = (f32x4){0.f, 0.f, 0.f, 0.f};

  bf16x8 b0[8], b1[8], a[2];
#pragma unroll
  for (int j = 0; j < 8; ++j) b0[j] = *(const bf16x8*)(bp[j]);
#pragma unroll
  for (int j = 0; j < 8; ++j) b1[j] = *(const bf16x8*)(bp[j] + 32);

#pragma unroll
  for (int t = 0; t < 16; t += 2) {
#pragma unroll
    for (int i = 0; i < 2; ++i)
      a[i] = *(const bf16x8*)(hsA + (rowbase + i * 16 + ln) * HSTR + t * 32 + q * 8);
#pragma unroll
    for (int i = 0; i < 2; ++i)
#pragma unroll
      for (int j = 0; j < 8; ++j)
        acc[i][j] = __builtin_amdgcn_mfma_f32_16x16x32_bf16(a[i], b0[j], acc[i][j], 0, 0, 0);
    if (t + 2 < 16) {
#pragma unroll
      for (int j = 0; j < 8; ++j) b0[j] = *(const bf16x8*)(bp[j] + (t + 2) * 32);
    }
#pragma unroll
    for (int i = 0; i < 2; ++i)
      a[i] = *(const bf16x8*)(hsA + (rowbase + i * 16 + ln) * HSTR + (t + 1) * 32 + q * 8);
#pragma unroll
    for (int i = 0; i < 2; ++i)
#pragma unroll
      for (int j = 0; j < 8; ++j)
        acc[i][j] = __builtin_amdgcn_mfma_f32_16x16x32_bf16(a[i], b1[j], acc[i][j], 0, 0, 0);
    if (t + 3 < 16) {
#pragma unroll
      for (int j = 0; j < 8; ++j) b1[j] = *(const bf16x8*)(bp[j] + (t + 3) * 32);
    }
  }

#pragma unroll
  for (int j = 0; j < 8; ++j) {
    const int col = colbase + j * 16 + ln;
#pragma unroll
    for (int i = 0; i < 2; ++i)
#pragma unroll
      for (int r = 0; r < 4; ++r) {
        const int row = rowbase + i * 16 + q * 4 + r;
        const float v = acc[i][j][r] + bj[j];
        const int o = row * HSTR + col;
        if (TANH)
          hsOut[o] = __float2bfloat16(fast_tanh(v));
        else
          hsOut[o] = __float2bfloat16(__bfloat162float(hsOut[o]) + DTC * v);
      }
  }
}

// One launch = 2 full Euler steps for a 64-row strip of h (row-local ODE).
// grid 256 x 512 threads, 130KB dynamic LDS, 1 block/CU, 2 waves/SIMD.
__global__ __launch_bounds__(512, 2) void k_euler2(
    bf16_t* __restrict__ h, const bf16_t* __restrict__ Wo1,
    const float* __restrict__ bo1, const bf16_t* __restrict__ Wo2,
    const float* __restrict__ bo2)
{
  extern __shared__ bf16_t sm[];
  bf16_t* hs = sm;               // [64][HSTR]
  bf16_t* Us = sm + 64 * HSTR;   // [64][HSTR]
  const int tid = threadIdx.x, wv = tid >> 6, lane = tid & 63;
  const int row0 = blockIdx.x * 64;
  const int scol = (tid & 63) * 8;

#pragma unroll
  for (int c = 0; c < 8; ++c) {
    const int row = c * 8 + wv;
    *(uint4*)(hs + row * HSTR + scol) =
        *(const uint4*)(h + (size_t)(row0 + row) * HS + scol);
  }
  __syncthreads();

  for (int s = 0; s < 2; ++s) {
    euler_pass<true >(Wo1, bo1, hs, Us, wv, lane);
    __syncthreads();
    euler_pass<false>(Wo2, bo2, Us, hs, wv, lane);
    __syncthreads();
  }

#pragma unroll
  for (int c = 0; c < 8; ++c) {
    const int row = c * 8 + wv;
    *(uint4*)(h + (size_t)(row0 + row) * HS + scol) =
        *(const uint4*)(hs + row * HSTR + scol);
  }
}

// ---------------------------------------------------------------------------
// m97-style staged GEMM pieces (obs kernels) — unchanged from round 5
// ---------------------------------------------------------------------------
template <int IT, int JT>
__device__ __forceinline__ void mfma_half(
    f32x4 (&acc)[IT][JT], const bf16_t* Ah, const bf16_t* Bh,
    int wr, int wc, int q, int ln)
{
  bf16x8 a[IT], b[JT];
#pragma unroll
  for (int i = 0; i < IT; ++i)
    a[i] = *(const bf16x8*)(Ah + (wr + i * 16 + ln) * 32 + q * 8);
#pragma unroll
  for (int j = 0; j < JT; ++j)
    b[j] = *(const bf16x8*)(Bh + (wc + j * 16 + ln) * 32 + q * 8);
#pragma unroll
  for (int i = 0; i < IT; ++i)
#pragma unroll
    for (int j = 0; j < JT; ++j)
      acc[i][j] = __builtin_amdgcn_mfma_f32_16x16x32_bf16(a[i], b[j], acc[i][j], 0, 0, 0);
}

__device__ __forceinline__ void loop128(
    f32x4 (&acc)[4][4],
    const bf16_t* __restrict__ A, int lda, const int* __restrict__ idx, int row0,
    const bf16_t* __restrict__ W, int ldw, int col0, int K,
    bf16_t* As, bf16_t* Bs)
{
  const int tid = threadIdx.x, wave = tid >> 6, lane = tid & 63;
  const int q = lane >> 4, ln = lane & 15;
  const int wr = (wave >> 1) * 64, wc = (wave & 1) * 64;
  const int srow = wave * 16 + (lane >> 2);
  const int skc  = (lane & 3) * 8;
  int ar0 = row0 + srow, ar1 = row0 + srow + 64;
  if (idx) { ar0 = idx[ar0]; ar1 = idx[ar1]; }
  const bf16_t* Ap0 = A + (size_t)ar0 * lda + skc;
  const bf16_t* Ap1 = A + (size_t)ar1 * lda + skc;
  const bf16_t* Bp0 = W + (size_t)(col0 + srow) * ldw + skc;
  const bf16_t* Bp1 = W + (size_t)(col0 + srow + 64) * ldw + skc;
  const int d0 = srow * 32 + skc, d1 = (srow + 64) * 32 + skc;

  for (int k0 = 0; k0 < K; k0 += 128) {
    __syncthreads();
#pragma unroll
    for (int s = 0; s < 4; ++s) {
      async16(Ap0 + k0 + s * 32, As + s * 4096 + d0);
      async16(Ap1 + k0 + s * 32, As + s * 4096 + d1);
      async16(Bp0 + k0 + s * 32, Bs + s * 4096 + d0);
      async16(Bp1 + k0 + s * 32, Bs + s * 4096 + d1);
    }
    __syncthreads();
#pragma unroll
    for (int s = 0; s < 4; ++s)
      mfma_half<4, 4>(acc, As + s * 4096, Bs + s * 4096, wr, wc, q, ln);
  }
}

__device__ __forceinline__ void loop64(
    f32x4 (&acc)[2][2],
    const bf16_t* __restrict__ A, int lda, int row0,
    const bf16_t* __restrict__ W, int ldw, int col0, int K,
    bf16_t* As, bf16_t* Bs)
{
  const int tid = threadIdx.x, wave = tid >> 6, lane = tid & 63;
  const int q = lane >> 4, ln = lane & 15;
  const int wr = (wave >> 1) * 32, wc = (wave & 1) * 32;
  const int srow = tid >> 2;
  const int skc  = (tid & 3) * 8;
  const bf16_t* Ap = A + (size_t)(row0 + srow) * lda + skc;
  const bf16_t* Bp = W + (size_t)(col0 + srow) * ldw + skc;
  bf16_t* As0 = As;           bf16_t* As1 = As + 64 * 32;
  bf16_t* Bs0 = Bs;           bf16_t* Bs1 = Bs + 64 * 32;
  const int d = srow * 32 + skc;

  for (int k0 = 0; k0 < K; k0 += 64) {
    __syncthreads();
    async16(Ap + k0,      As0 + d);
    async16(Bp + k0,      Bs0 + d);
    async16(Ap + k0 + 32, As1 + d);
    async16(Bp + k0 + 32, Bs1 + d);
    __syncthreads();
    mfma_half<2, 2>(acc, As0, Bs0, wr, wc, q, ln);
    mfma_half<2, 2>(acc, As1, Bs1, wr, wc, q, ln);
  }
}

// Fused: z==0 -> tmpE = relu(h[idx] @ Wp1^T + bp1)
//        z==1 -> hnewE = tanh(Xk @ Wih^T + b_ih + h[idx] @ Whh^T + b_hh)
__global__ __launch_bounds__(256) void k_obs_pre(
    const bf16_t* __restrict__ h, const int* __restrict__ idx,
    const bf16_t* __restrict__ Wp1, const float* __restrict__ bp1,
    bf16_t* __restrict__ tmpE,
    const float* __restrict__ Xk,
    const bf16_t* __restrict__ Wih, const float* __restrict__ b_ih,
    const bf16_t* __restrict__ Whh, const float* __restrict__ b_hh,
    bf16_t* __restrict__ hnewE)
{
  __shared__ bf16_t As[128 * 128], Bs[128 * 128];
  f32x4 acc[4][4] = {};
  const int tid = threadIdx.x, wave = tid >> 6, lane = tid & 63;
  const int q = lane >> 4, ln = lane & 15;
  const int wr = (wave >> 1) * 64, wc = (wave & 1) * 64;
  const int row0 = blockIdx.x * 128, col0 = blockIdx.y * 128;

  if (blockIdx.z == 0) {
    loop128(acc, h, HS, idx, row0, Wp1, HS, col0, HS, As, Bs);
#pragma unroll
    for (int j = 0; j < 4; ++j) {
      const int c = col0 + wc + j * 16 + ln;
      const float bj = bp1[c];
#pragma unroll
      for (int i = 0; i < 4; ++i)
#pragma unroll
        for (int r = 0; r < 4; ++r) {
          const int rw = row0 + wr + i * 16 + q * 4 + r;
          const float v = acc[i][j][r] + bj;
          tmpE[(size_t)rw * HS + c] = __float2bfloat16(v > 0.f ? v : 0.f);
        }
    }
  } else {
    {
      const int srow = wave * 16 + (lane >> 2);
      const int skc  = (lane & 3) * 8;
      const bf16_t* Bp0 = Wih + (size_t)(col0 + srow) * DS + skc;
      const bf16_t* Bp1 = Wih + (size_t)(col0 + srow + 64) * DS + skc;
      bf16_t* lB0 = Bs + srow * 32 + skc;
      bf16_t* lB1 = Bs + (srow + 64) * 32 + skc;
      const int xr = tid >> 1, xh = (tid & 1) * 16;
      for (int k0 = 0; k0 < DS; k0 += 32) {
        __syncthreads();
        async16(Bp0 + k0, lB0);
        async16(Bp1 + k0, lB1);
        {
          const float* s = Xk + (size_t)(row0 + xr) * DS + k0 + xh;
          __attribute__((aligned(16))) bf16_t buf[16];
#pragma unroll
          for (int u = 0; u < 16; ++u) buf[u] = __float2bfloat16(s[u]);
          *(uint4*)(As + xr * 32 + xh)     = *(const uint4*)buf;
          *(uint4*)(As + xr * 32 + xh + 8) = *(const uint4*)(buf + 8);
        }
        __syncthreads();
        mfma_half<4, 4>(acc, As, Bs, wr, wc, q, ln);
      }
    }
    loop128(acc, h, HS, idx, row0, Whh, HS, col0, HS, As, Bs);
#pragma unroll
    for (int j = 0; j < 4; ++j) {
      const int c = col0 + wc + j * 16 + ln;
      const float bj = b_ih[c] + b_hh[c];
#pragma unroll
      for (int i = 0; i < 4; ++i)
#pragma unroll
        for (int r = 0; r < 4; ++r) {
          const int rw = row0 + wr + i * 16 + q * 4 + r;
          hnewE[(size_t)rw * HS + c] = __float2bfloat16(fast_tanh(acc[i][j][r] + bj));
        }
    }
  }
}

// Fused: blocks [0,128) -> loss; [128,1152) -> scatter
__global__ __launch_bounds__(256) void k_obs_post(
    const bf16_t* __restrict__ tmpE, const bf16_t* __restrict__ Wp2,
    const float* __restrict__ bp2, const float* __restrict__ X,
    const float* __restrict__ Mm, float* __restrict__ accum,
    bf16_t* __restrict__ h, const bf16_t* __restrict__ hnewE,
    const int* __restrict__ idx)
{
  const int bid = blockIdx.x;
  if (bid >= 128) {
    const int t  = (bid - 128) * 256 + threadIdx.x;
    const int r  = t >> 6;
    const int c8 = (t & 63) * 8;
    const int gr = idx[r];
    *(uint4*)(h + (size_t)gr * HS + c8) = *(const uint4*)(hnewE + (size_t)r * HS + c8);
    return;
  }
  __shared__ bf16_t As[64 * 64], Bs[64 * 64];
  f32x4 acc[2][2] = {};
  const int wave = threadIdx.x >> 6, lane = threadIdx.x & 63;
  const int q = lane >> 4, ln = lane & 15;
  const int wr = (wave >> 1) * 32, wc = (wave & 1) * 32;
  const int row0 = (bid >> 1) * 64, col0 = (bid & 1) * 64;
  loop64(acc, tmpE, HS, row0, Wp2, HS, col0, HS, As, Bs);
  float ls = 0.f;
#pragma unroll
  for (int j = 0; j < 2; ++j) {
    const int c = col0 + wc + j * 16 + ln;
    const float bj = bp2[c];
#pragma unroll
    for (int i = 0; i < 2; ++i)
#pragma unroll
      for (int r = 0; r < 4; ++r) {
        const int rw = row0 + wr + i * 16 + q * 4 + r;
        const float p = acc[i][j][r] + bj;
        const size_t o = (size_t)rw * DS + c;
        ls += fabsf(X[o] - p) * Mm[o];
      }
  }
#pragma unroll
  for (int off = 32; off > 0; off >>= 1) ls += __shfl_down(ls, off);
  __shared__ float red[4];
  if (lane == 0) red[wave] = ls;
  __syncthreads();
  if (threadIdx.x == 0) atomicAdd(accum, red[0] + red[1] + red[2] + red[3]);
}

__global__ void k_cvt(const float* __restrict__ s, bf16_t* __restrict__ d, int n)
{
  const int i = blockIdx.x * 256 + threadIdx.x;
  if (i * 4 < n) {
    const float4 v = ((const float4*)s)[i];
    d[i * 4 + 0] = __float2bfloat16(v.x);
    d[i * 4 + 1] = __float2bfloat16(v.y);
    d[i * 4 + 2] = __float2bfloat16(v.z);
    d[i * 4 + 3] = __float2bfloat16(v.w);
  }
}

__global__ void k_zero(float* __restrict__ p, size_t n4)
{
  size_t i = (size_t)blockIdx.x * blockDim.x + threadIdx.x;
  const size_t st = (size_t)gridDim.x * blockDim.x;
  const float4 z = {0.f, 0.f, 0.f, 0.f};
  for (; i < n4; i += st) ((float4*)p)[i] = z;
}

__global__ void k_zero_accum(float* accum)
{
  if (threadIdx.x < 2) accum[threadIdx.x] = 0.f;
}

__global__ void k_sum(const float* __restrict__ M, size_t n4, float* __restrict__ accum)
{
  __shared__ float red[256];
  float s = 0.f;
  for (size_t i = (size_t)blockIdx.x * blockDim.x + threadIdx.x; i < n4;
       i += (size_t)gridDim.x * blockDim.x) {
    const float4 v = ((const float4*)M)[i];
    s += v.x + v.y + v.z + v.w;
  }
  red[threadIdx.x] = s;
  __syncthreads();
  for (int st = 128; st > 0; st >>= 1) {
    if (threadIdx.x < st) red[threadIdx.x] += red[threadIdx.x + st];
    __syncthreads();
  }
  if (threadIdx.x == 0) atomicAdd(accum + 1, red[0]);
}

__global__ void k_final(const float* __restrict__ accum, float* __restrict__ out)
{
  out[0] = accum[0];
  out[1] = accum[0] / accum[1];
}

// ---------------------------------------------------------------------------
extern "C" void kernel_launch(void* const* d_in, const int* in_sizes, int n_in,
                              void* d_out, int out_size, void* d_ws, size_t ws_size,
                              hipStream_t stream)
{
  const float* X    = (const float*)d_in[0];
  const float* M    = (const float*)d_in[1];
  const int*   bidx = (const int*)d_in[2];
  const float* W_ih = (const float*)d_in[3];
  const float* b_ih = (const float*)d_in[4];
  const float* W_hh = (const float*)d_in[5];
  const float* b_hh = (const float*)d_in[6];
  const float* Wo1  = (const float*)d_in[7];
  const float* bo1  = (const float*)d_in[8];
  const float* Wo2  = (const float*)d_in[9];
  const float* bo2  = (const float*)d_in[10];
  const float* Wp1  = (const float*)d_in[11];
  const float* bp1  = (const float*)d_in[12];
  const float* Wp2  = (const float*)d_in[13];
  const float* bp2  = (const float*)d_in[14];
  float* out = (float*)d_out;

  char* w = (char*)d_ws;
  bf16_t* h     = (bf16_t*)w;                         w += (size_t)NS * HS * 2;
  bf16_t* tmp   = (bf16_t*)w;                         w += (size_t)NS * HS * 2;
  bf16_t* tmpE  = (bf16_t*)w;                         w += (size_t)ES * HS * 2;
  bf16_t* hnewE = (bf16_t*)w;                         w += (size_t)ES * HS * 2;
  bf16_t* wWo1  = (bf16_t*)w;                         w += (size_t)HS * HS * 2;
  bf16_t* wWo2  = (bf16_t*)w;                         w += (size_t)HS * HS * 2;
  bf16_t* wWp1  = (bf16_t*)w;                         w += (size_t)HS * HS * 2;
  bf16_t* wWp2  = (bf16_t*)w;                         w += (size_t)DS * HS * 2;
  bf16_t* wWih  = (bf16_t*)w;                         w += (size_t)HS * DS * 2;
  bf16_t* wWhh  = (bf16_t*)w;                         w += (size_t)HS * HS * 2;
  float*  accum = (float*)w;
  (void)tmp;

  const int eulerLds = 2 * 64 * HSTR * 2;  // hs + Us, bf16
  hipFuncSetAttribute((const void*)k_euler2,
                      hipFuncAttributeMaxDynamicSharedMemorySize, eulerLds);

  k_zero<<<2048, 256, 0, stream>>>((float*)h, (size_t)NS * HS * 2 / 16);
  k_zero_accum<<<1, 64, 0, stream>>>(accum);
  k_sum<<<2048, 256, 0, stream>>>(M, (size_t)KOBS * ES * DS / 4, accum);
  k_cvt<<<256, 256, 0, stream>>>(Wo1, wWo1, HS * HS);
  k_cvt<<<256, 256, 0, stream>>>(Wo2, wWo2, HS * HS);
  k_cvt<<<256, 256, 0, stream>>>(Wp1, wWp1, HS * HS);
  k_cvt<<<64, 256, 0, stream>>>(Wp2, wWp2, DS * HS);
  k_cvt<<<64, 256, 0, stream>>>(W_ih, wWih, HS * DS);
  k_cvt<<<256, 256, 0, stream>>>(W_hh, wWhh, HS * HS);

  const dim3 gPre(ES / 128, HS / 128, 2); // 256 blocks
  const int  gPost = 128 + ES * HS / 8 / 256;

  for (int k = 0; k < KOBS; ++k) {
    const int*   idx = bidx + (size_t)k * ES;
    const float* Xk  = X + (size_t)k * ES * DS;
    const float* Mk  = M + (size_t)k * ES * DS;

    k_euler2<<<NS / 64, 512, eulerLds, stream>>>(h, wWo1, bo1, wWo2, bo2);
    k_obs_pre <<<gPre, 256, 0, stream>>>(h, idx, wWp1, bp1, tmpE,
                                         Xk, wWih, b_ih, wWhh, b_hh, hnewE);
    k_obs_post<<<gPost, 256, 0, stream>>>(tmpE, wWp2, bp2, Xk, Mk, accum,
                                          h, hnewE, idx);
  }

  k_final<<<1, 1, 0, stream>>>(accum, out);
}

// Round 7
// 3872.074 us; speedup vs baseline: 4.6882x; 4.6882x over previous
//
#include <hip/hip_runtime.h>
#include <hip/hip_bf16.h>
#include <cstddef>
#include <cstdint>

#define NS   16384
#define HS   512
#define DS   128
#define KOBS 40
#define ES   4096
#define DTC  0.05f

typedef __bf16 bf16x8 __attribute__((ext_vector_type(8)));
typedef float  f32x4  __attribute__((ext_vector_type(4)));
typedef __hip_bfloat16 bf16_t;

__device__ __forceinline__ void async16(const void* g, void* l)
{
  __builtin_amdgcn_global_load_lds(
      (const __attribute__((address_space(1))) unsigned int*)g,
      (__attribute__((address_space(3))) unsigned int*)l, 16, 0, 0);
}

// fast tanh: 1 - 2/(1+e^{2x}); |err| ~1e-7 rel, far below bf16 quantization.
__device__ __forceinline__ float fast_tanh(float x)
{
  return 1.f - 2.f / (1.f + __expf(2.f * x));
}

// ---------------------------------------------------------------------------
// One BK=32 half-step from a [rows][32] LDS tile pair (64B row stride).
// A-frag: lane holds A[m=ln][k=q*8+0..7]; C/D: col=ln, row=q*4+r.
// ---------------------------------------------------------------------------
template <int IT, int JT>
__device__ __forceinline__ void mfma_half(
    f32x4 (&acc)[IT][JT], const bf16_t* Ah, const bf16_t* Bh,
    int wr, int wc, int q, int ln)
{
  bf16x8 a[IT], b[JT];
#pragma unroll
  for (int i = 0; i < IT; ++i)
    a[i] = *(const bf16x8*)(Ah + (wr + i * 16 + ln) * 32 + q * 8);
#pragma unroll
  for (int j = 0; j < JT; ++j)
    b[j] = *(const bf16x8*)(Bh + (wc + j * 16 + ln) * 32 + q * 8);
#pragma unroll
  for (int i = 0; i < IT; ++i)
#pragma unroll
    for (int j = 0; j < JT; ++j)
      acc[i][j] = __builtin_amdgcn_mfma_f32_16x16x32_bf16(a[i], b[j], acc[i][j], 0, 0, 0);
}

// ---------------------------------------------------------------------------
// BK=128 K-loop, 128x128 block tile, 256 threads. As/Bs are [128*128] bf16,
// four [128][32] sub-buffers each.
// ---------------------------------------------------------------------------
__device__ __forceinline__ void loop128(
    f32x4 (&acc)[4][4],
    const bf16_t* __restrict__ A, int lda, const int* __restrict__ idx, int row0,
    const bf16_t* __restrict__ W, int ldw, int col0, int K,
    bf16_t* As, bf16_t* Bs)
{
  const int tid = threadIdx.x, wave = tid >> 6, lane = tid & 63;
  const int q = lane >> 4, ln = lane & 15;
  const int wr = (wave >> 1) * 64, wc = (wave & 1) * 64;
  const int srow = wave * 16 + (lane >> 2);
  const int skc  = (lane & 3) * 8;
  int ar0 = row0 + srow, ar1 = row0 + srow + 64;
  if (idx) { ar0 = idx[ar0]; ar1 = idx[ar1]; }
  const bf16_t* Ap0 = A + (size_t)ar0 * lda + skc;
  const bf16_t* Ap1 = A + (size_t)ar1 * lda + skc;
  const bf16_t* Bp0 = W + (size_t)(col0 + srow) * ldw + skc;
  const bf16_t* Bp1 = W + (size_t)(col0 + srow + 64) * ldw + skc;
  const int d0 = srow * 32 + skc, d1 = (srow + 64) * 32 + skc;

  for (int k0 = 0; k0 < K; k0 += 128) {
    __syncthreads();
#pragma unroll
    for (int s = 0; s < 4; ++s) {
      async16(Ap0 + k0 + s * 32, As + s * 4096 + d0);
      async16(Ap1 + k0 + s * 32, As + s * 4096 + d1);
      async16(Bp0 + k0 + s * 32, Bs + s * 4096 + d0);
      async16(Bp1 + k0 + s * 32, Bs + s * 4096 + d1);
    }
    __syncthreads();
#pragma unroll
    for (int s = 0; s < 4; ++s)
      mfma_half<4, 4>(acc, As + s * 4096, Bs + s * 4096, wr, wc, q, ln);
  }
}

// BK=64 K-loop, 64x64 block tile, 256 threads.
__device__ __forceinline__ void loop64(
    f32x4 (&acc)[2][2],
    const bf16_t* __restrict__ A, int lda, int row0,
    const bf16_t* __restrict__ W, int ldw, int col0, int K,
    bf16_t* As, bf16_t* Bs)
{
  const int tid = threadIdx.x, wave = tid >> 6, lane = tid & 63;
  const int q = lane >> 4, ln = lane & 15;
  const int wr = (wave >> 1) * 32, wc = (wave & 1) * 32;
  const int srow = tid >> 2;
  const int skc  = (tid & 3) * 8;
  const bf16_t* Ap = A + (size_t)(row0 + srow) * lda + skc;
  const bf16_t* Bp = W + (size_t)(col0 + srow) * ldw + skc;
  bf16_t* As0 = As;           bf16_t* As1 = As + 64 * 32;
  bf16_t* Bs0 = Bs;           bf16_t* Bs1 = Bs + 64 * 32;
  const int d = srow * 32 + skc;

  for (int k0 = 0; k0 < K; k0 += 64) {
    __syncthreads();
    async16(Ap + k0,      As0 + d);
    async16(Bp + k0,      Bs0 + d);
    async16(Ap + k0 + 32, As1 + d);
    async16(Bp + k0 + 32, Bs1 + d);
    __syncthreads();
    mfma_half<2, 2>(acc, As0, Bs0, wr, wc, q, ln);
    mfma_half<2, 2>(acc, As1, Bs1, wr, wc, q, ln);
  }
}

// ---------------------------------------------------------------------------
// Kernels
// ---------------------------------------------------------------------------

// tmp = tanh(h @ Wo1^T + bo1)   grid (NS/128, HS/128)
__global__ __launch_bounds__(256) void k_gemm_tanh(
    const bf16_t* __restrict__ A, const bf16_t* __restrict__ W,
    const float* __restrict__ bias, bf16_t* __restrict__ out)
{
  __shared__ bf16_t As[128 * 128], Bs[128 * 128];
  f32x4 acc[4][4] = {};
  const int wave = threadIdx.x >> 6, lane = threadIdx.x & 63;
  const int q = lane >> 4, ln = lane & 15;
  const int wr = (wave >> 1) * 64, wc = (wave & 1) * 64;
  const int row0 = blockIdx.x * 128, col0 = blockIdx.y * 128;
  loop128(acc, A, HS, nullptr, row0, W, HS, col0, HS, As, Bs);
#pragma unroll
  for (int j = 0; j < 4; ++j) {
    const int c = col0 + wc + j * 16 + ln;
    const float bj = bias[c];
#pragma unroll
    for (int i = 0; i < 4; ++i)
#pragma unroll
      for (int r = 0; r < 4; ++r) {
        const int rw = row0 + wr + i * 16 + q * 4 + r;
        out[(size_t)rw * HS + c] = __float2bfloat16(fast_tanh(acc[i][j][r] + bj));
      }
  }
}

// h = h + DT * (tmp @ Wo2^T + bo2)
__global__ __launch_bounds__(256) void k_gemm_resid(
    const bf16_t* __restrict__ A, const bf16_t* __restrict__ W,
    const float* __restrict__ bias, bf16_t* __restrict__ h)
{
  __shared__ bf16_t As[128 * 128], Bs[128 * 128];
  f32x4 acc[4][4] = {};
  const int wave = threadIdx.x >> 6, lane = threadIdx.x & 63;
  const int q = lane >> 4, ln = lane & 15;
  const int wr = (wave >> 1) * 64, wc = (wave & 1) * 64;
  const int row0 = blockIdx.x * 128, col0 = blockIdx.y * 128;
  loop128(acc, A, HS, nullptr, row0, W, HS, col0, HS, As, Bs);
#pragma unroll
  for (int j = 0; j < 4; ++j) {
    const int c = col0 + wc + j * 16 + ln;
    const float bj = bias[c];
#pragma unroll
    for (int i = 0; i < 4; ++i)
#pragma unroll
      for (int r = 0; r < 4; ++r) {
        const int rw = row0 + wr + i * 16 + q * 4 + r;
        const size_t o = (size_t)rw * HS + c;
        h[o] = __float2bfloat16(__bfloat162float(h[o]) + DTC * (acc[i][j][r] + bj));
      }
  }
}

// Fused: z==0 -> tmpE = relu(h[idx] @ Wp1^T + bp1)
//        z==1 -> hnewE = tanh(Xk @ Wih^T + b_ih + h[idx] @ Whh^T + b_hh)
__global__ __launch_bounds__(256) void k_obs_pre(
    const bf16_t* __restrict__ h, const int* __restrict__ idx,
    const bf16_t* __restrict__ Wp1, const float* __restrict__ bp1,
    bf16_t* __restrict__ tmpE,
    const float* __restrict__ Xk,
    const bf16_t* __restrict__ Wih, const float* __restrict__ b_ih,
    const bf16_t* __restrict__ Whh, const float* __restrict__ b_hh,
    bf16_t* __restrict__ hnewE)
{
  __shared__ bf16_t As[128 * 128], Bs[128 * 128];
  f32x4 acc[4][4] = {};
  const int tid = threadIdx.x, wave = tid >> 6, lane = tid & 63;
  const int q = lane >> 4, ln = lane & 15;
  const int wr = (wave >> 1) * 64, wc = (wave & 1) * 64;
  const int row0 = blockIdx.x * 128, col0 = blockIdx.y * 128;

  if (blockIdx.z == 0) {
    loop128(acc, h, HS, idx, row0, Wp1, HS, col0, HS, As, Bs);
#pragma unroll
    for (int j = 0; j < 4; ++j) {
      const int c = col0 + wc + j * 16 + ln;
      const float bj = bp1[c];
#pragma unroll
      for (int i = 0; i < 4; ++i)
#pragma unroll
        for (int r = 0; r < 4; ++r) {
          const int rw = row0 + wr + i * 16 + q * 4 + r;
          const float v = acc[i][j][r] + bj;
          tmpE[(size_t)rw * HS + c] = __float2bfloat16(v > 0.f ? v : 0.f);
        }
    }
  } else {
    // phase 1: Xk (fp32) @ Wih^T, K = DS = 128, single BK=128 barrier pair
    {
      const int srow = wave * 16 + (lane >> 2);
      const int skc  = (lane & 3) * 8;
      const bf16_t* Bp0 = Wih + (size_t)(col0 + srow) * DS + skc;
      const bf16_t* Bp1 = Wih + (size_t)(col0 + srow + 64) * DS + skc;
      const int d0 = srow * 32 + skc, d1 = (srow + 64) * 32 + skc;
      const int xr = tid >> 1, xh = (tid & 1) * 16;
#pragma unroll
      for (int s = 0; s < 4; ++s) {
        async16(Bp0 + s * 32, Bs + s * 4096 + d0);
        async16(Bp1 + s * 32, Bs + s * 4096 + d1);
      }
#pragma unroll
      for (int s = 0; s < 4; ++s) {
        const float* src = Xk + (size_t)(row0 + xr) * DS + s * 32 + xh;
        __attribute__((aligned(16))) bf16_t buf[16];
#pragma unroll
        for (int u = 0; u < 16; ++u) buf[u] = __float2bfloat16(src[u]);
        *(uint4*)(As + s * 4096 + xr * 32 + xh)     = *(const uint4*)buf;
        *(uint4*)(As + s * 4096 + xr * 32 + xh + 8) = *(const uint4*)(buf + 8);
      }
      __syncthreads();
#pragma unroll
      for (int s = 0; s < 4; ++s)
        mfma_half<4, 4>(acc, As + s * 4096, Bs + s * 4096, wr, wc, q, ln);
    }
    // phase 2: h[idx] @ Whh^T, K = HS (loop128's leading barrier protects As)
    loop128(acc, h, HS, idx, row0, Whh, HS, col0, HS, As, Bs);
#pragma unroll
    for (int j = 0; j < 4; ++j) {
      const int c = col0 + wc + j * 16 + ln;
      const float bj = b_ih[c] + b_hh[c];
#pragma unroll
      for (int i = 0; i < 4; ++i)
#pragma unroll
        for (int r = 0; r < 4; ++r) {
          const int rw = row0 + wr + i * 16 + q * 4 + r;
          hnewE[(size_t)rw * HS + c] = __float2bfloat16(fast_tanh(acc[i][j][r] + bj));
        }
    }
  }
}

// Fused: blocks [0,128) -> loss GEMM; [128,1152) -> scatter
__global__ __launch_bounds__(256) void k_obs_post(
    const bf16_t* __restrict__ tmpE, const bf16_t* __restrict__ Wp2,
    const float* __restrict__ bp2, const float* __restrict__ X,
    const float* __restrict__ Mm, float* __restrict__ accum,
    bf16_t* __restrict__ h, const bf16_t* __restrict__ hnewE,
    const int* __restrict__ idx)
{
  const int bid = blockIdx.x;
  if (bid >= 128) {
    const int t  = (bid - 128) * 256 + threadIdx.x;
    const int r  = t >> 6;
    const int c8 = (t & 63) * 8;
    const int gr = idx[r];
    *(uint4*)(h + (size_t)gr * HS + c8) = *(const uint4*)(hnewE + (size_t)r * HS + c8);
    return;
  }
  __shared__ bf16_t As[64 * 64], Bs[64 * 64];
  f32x4 acc[2][2] = {};
  const int wave = threadIdx.x >> 6, lane = threadIdx.x & 63;
  const int q = lane >> 4, ln = lane & 15;
  const int wr = (wave >> 1) * 32, wc = (wave & 1) * 32;
  const int row0 = (bid >> 1) * 64, col0 = (bid & 1) * 64;
  loop64(acc, tmpE, HS, row0, Wp2, HS, col0, HS, As, Bs);
  float ls = 0.f;
#pragma unroll
  for (int j = 0; j < 2; ++j) {
    const int c = col0 + wc + j * 16 + ln;
    const float bj = bp2[c];
#pragma unroll
    for (int i = 0; i < 2; ++i)
#pragma unroll
      for (int r = 0; r < 4; ++r) {
        const int rw = row0 + wr + i * 16 + q * 4 + r;
        const float p = acc[i][j][r] + bj;
        const size_t o = (size_t)rw * DS + c;
        ls += fabsf(X[o] - p) * Mm[o];
      }
  }
#pragma unroll
  for (int off = 32; off > 0; off >>= 1) ls += __shfl_down(ls, off);
  __shared__ float red[4];
  if (lane == 0) red[wave] = ls;
  __syncthreads();
  if (threadIdx.x == 0) atomicAdd(accum, red[0] + red[1] + red[2] + red[3]);
}

__global__ void k_cvt(const float* __restrict__ s, bf16_t* __restrict__ d, int n)
{
  const int i = blockIdx.x * 256 + threadIdx.x;
  if (i * 4 < n) {
    const float4 v = ((const float4*)s)[i];
    d[i * 4 + 0] = __float2bfloat16(v.x);
    d[i * 4 + 1] = __float2bfloat16(v.y);
    d[i * 4 + 2] = __float2bfloat16(v.z);
    d[i * 4 + 3] = __float2bfloat16(v.w);
  }
}

__global__ void k_zero(float* __restrict__ p, size_t n4)
{
  size_t i = (size_t)blockIdx.x * blockDim.x + threadIdx.x;
  const size_t st = (size_t)gridDim.x * blockDim.x;
  const float4 z = {0.f, 0.f, 0.f, 0.f};
  for (; i < n4; i += st) ((float4*)p)[i] = z;
}

__global__ void k_zero_accum(float* accum)
{
  if (threadIdx.x < 2) accum[threadIdx.x] = 0.f;
}

__global__ void k_sum(const float* __restrict__ M, size_t n4, float* __restrict__ accum)
{
  __shared__ float red[256];
  float s = 0.f;
  for (size_t i = (size_t)blockIdx.x * blockDim.x + threadIdx.x; i < n4;
       i += (size_t)gridDim.x * blockDim.x) {
    const float4 v = ((const float4*)M)[i];
    s += v.x + v.y + v.z + v.w;
  }
  red[threadIdx.x] = s;
  __syncthreads();
  for (int st = 128; st > 0; st >>= 1) {
    if (threadIdx.x < st) red[threadIdx.x] += red[threadIdx.x + st];
    __syncthreads();
  }
  if (threadIdx.x == 0) atomicAdd(accum + 1, red[0]);
}

__global__ void k_final(const float* __restrict__ accum, float* __restrict__ out)
{
  out[0] = accum[0];
  out[1] = accum[0] / accum[1];
}

// ---------------------------------------------------------------------------
extern "C" void kernel_launch(void* const* d_in, const int* in_sizes, int n_in,
                              void* d_out, int out_size, void* d_ws, size_t ws_size,
                              hipStream_t stream)
{
  const float* X    = (const float*)d_in[0];
  const float* M    = (const float*)d_in[1];
  const int*   bidx = (const int*)d_in[2];
  const float* W_ih = (const float*)d_in[3];
  const float* b_ih = (const float*)d_in[4];
  const float* W_hh = (const float*)d_in[5];
  const float* b_hh = (const float*)d_in[6];
  const float* Wo1  = (const float*)d_in[7];
  const float* bo1  = (const float*)d_in[8];
  const float* Wo2  = (const float*)d_in[9];
  const float* bo2  = (const float*)d_in[10];
  const float* Wp1  = (const float*)d_in[11];
  const float* bp1  = (const float*)d_in[12];
  const float* Wp2  = (const float*)d_in[13];
  const float* bp2  = (const float*)d_in[14];
  float* out = (float*)d_out;

  char* w = (char*)d_ws;
  bf16_t* h     = (bf16_t*)w;                         w += (size_t)NS * HS * 2;
  bf16_t* tmp   = (bf16_t*)w;                         w += (size_t)NS * HS * 2;
  bf16_t* tmpE  = (bf16_t*)w;                         w += (size_t)ES * HS * 2;
  bf16_t* hnewE = (bf16_t*)w;                         w += (size_t)ES * HS * 2;
  bf16_t* wWo1  = (bf16_t*)w;                         w += (size_t)HS * HS * 2;
  bf16_t* wWo2  = (bf16_t*)w;                         w += (size_t)HS * HS * 2;
  bf16_t* wWp1  = (bf16_t*)w;                         w += (size_t)HS * HS * 2;
  bf16_t* wWp2  = (bf16_t*)w;                         w += (size_t)DS * HS * 2;
  bf16_t* wWih  = (bf16_t*)w;                         w += (size_t)HS * DS * 2;
  bf16_t* wWhh  = (bf16_t*)w;                         w += (size_t)HS * HS * 2;
  float*  accum = (float*)w;

  k_zero<<<2048, 256, 0, stream>>>((float*)h, (size_t)NS * HS * 2 / 16);
  k_zero_accum<<<1, 64, 0, stream>>>(accum);
  k_sum<<<2048, 256, 0, stream>>>(M, (size_t)KOBS * ES * DS / 4, accum);
  k_cvt<<<256, 256, 0, stream>>>(Wo1, wWo1, HS * HS);
  k_cvt<<<256, 256, 0, stream>>>(Wo2, wWo2, HS * HS);
  k_cvt<<<256, 256, 0, stream>>>(Wp1, wWp1, HS * HS);
  k_cvt<<<64, 256, 0, stream>>>(Wp2, wWp2, DS * HS);
  k_cvt<<<64, 256, 0, stream>>>(W_ih, wWih, HS * DS);
  k_cvt<<<256, 256, 0, stream>>>(W_hh, wWhh, HS * HS);

  const dim3 gE(NS / 128, HS / 128);      // 128 x 4 = 512 blocks
  const dim3 gPre(ES / 128, HS / 128, 2); // 32 x 4 x 2 = 256 blocks
  const int  gPost = 128 + ES * HS / 8 / 256;  // 128 loss + 1024 scatter

  for (int k = 0; k < KOBS; ++k) {
    const int*   idx = bidx + (size_t)k * ES;
    const float* Xk  = X + (size_t)k * ES * DS;
    const float* Mk  = M + (size_t)k * ES * DS;

    for (int s = 0; s < 2; ++s) {
      k_gemm_tanh <<<gE, 256, 0, stream>>>(h, wWo1, bo1, tmp);
      k_gemm_resid<<<gE, 256, 0, stream>>>(tmp, wWo2, bo2, h);
    }
    k_obs_pre <<<gPre, 256, 0, stream>>>(h, idx, wWp1, bp1, tmpE,
                                         Xk, wWih, b_ih, wWhh, b_hh, hnewE);
    k_obs_post<<<gPost, 256, 0, stream>>>(tmpE, wWp2, bp2, Xk, Mk, accum,
                                          h, hnewE, idx);
  }

  k_final<<<1, 1, 0, stream>>>(accum, out);
}